// Round 6
// baseline (328.229 us; speedup 1.0000x reference)
//
#include <hip/hip_runtime.h>

#define N_NODES 100000
#define N_EDGES 1600000
#define IN_CH   128
#define HEADS   4
#define OUT_CH  32
#define HID     128   // HEADS*OUT_CH
#define NEG_SLOPE 0.2f

#define BNODES  1024                      // nodes per bucket (pow2)
#define NBUCK   ((N_NODES + BNODES - 1) / BNODES)   // 98
#define NBLK    256                       // histogram / scatter blocks
#define EPB     (N_EDGES / NBLK)          // 6250 edges per block (exact)

typedef unsigned int  uint;
typedef unsigned short ushort;

// bf16 round-to-nearest-even pack
__device__ __forceinline__ ushort f2bf(float f) {
    uint u = __float_as_uint(f);
    return (ushort)((u + 0x7FFFu + ((u >> 16) & 1u)) >> 16);
}

// ---------------- K1: h = x @ W (fp32 compute, bf16 store) + fused att scores ----------------
#define BM 64
#define BK 32
__global__ __launch_bounds__(256) void k_gemm(const float* __restrict__ x,
                                              const float* __restrict__ w,
                                              const float* __restrict__ att,
                                              ushort* __restrict__ h,
                                              float* __restrict__ s_src,
                                              float* __restrict__ s_dst) {
    __shared__ float xs[BK][BM + 4];
    __shared__ float wsld[BK][HID + 4];
    __shared__ float sred[BM][8];          // [node][head*2 + {src,dst}]

    const int tid  = threadIdx.x;
    const int nodeBase = blockIdx.x * BM;
    const int c0 = (tid & 15) * 8;
    const int n0 = (tid >> 4) * 4;

    // zero score-reduction buffer (ordering guaranteed by K-loop's first syncthreads)
#pragma unroll
    for (int l = 0; l < 2; l++) {
        int idx = tid + l * 256;           // 0..511
        sred[idx >> 3][idx & 7] = 0.0f;
    }

    float acc[4][8];
#pragma unroll
    for (int i = 0; i < 4; i++)
#pragma unroll
        for (int j = 0; j < 8; j++) acc[i][j] = 0.0f;

    for (int k0 = 0; k0 < IN_CH; k0 += BK) {
#pragma unroll
        for (int l = 0; l < 2; l++) {
            int idx  = tid + l * 256;
            int row  = idx >> 3;
            int col4 = (idx & 7) * 4;
            int n = nodeBase + row;
            float4 v = make_float4(0.f, 0.f, 0.f, 0.f);
            if (n < N_NODES) v = *reinterpret_cast<const float4*>(x + (size_t)n * IN_CH + k0 + col4);
            xs[col4 + 0][row] = v.x;
            xs[col4 + 1][row] = v.y;
            xs[col4 + 2][row] = v.z;
            xs[col4 + 3][row] = v.w;
        }
#pragma unroll
        for (int l = 0; l < 4; l++) {
            int idx  = tid + l * 256;
            int row  = idx >> 5;
            int col4 = (idx & 31) * 4;
            float4 v = *reinterpret_cast<const float4*>(w + (size_t)(k0 + row) * HID + col4);
            *reinterpret_cast<float4*>(&wsld[row][col4]) = v;
        }
        __syncthreads();

#pragma unroll
        for (int kk = 0; kk < BK; kk++) {
            float4 xv = *reinterpret_cast<const float4*>(&xs[kk][n0]);
            float4 wa = *reinterpret_cast<const float4*>(&wsld[kk][c0]);
            float4 wb = *reinterpret_cast<const float4*>(&wsld[kk][c0 + 4]);
            float xr[4] = {xv.x, xv.y, xv.z, xv.w};
            float wr[8] = {wa.x, wa.y, wa.z, wa.w, wb.x, wb.y, wb.z, wb.w};
#pragma unroll
            for (int i = 0; i < 4; i++)
#pragma unroll
                for (int j = 0; j < 8; j++)
                    acc[i][j] = fmaf(xr[i], wr[j], acc[i][j]);
        }
        __syncthreads();
    }

    // ---- epilogue 1: bf16 store of h ----
#pragma unroll
    for (int i = 0; i < 4; i++) {
        int n = nodeBase + n0 + i;
        if (n < N_NODES) {
            uint4 pk;
            pk.x = (uint)f2bf(acc[i][0]) | ((uint)f2bf(acc[i][1]) << 16);
            pk.y = (uint)f2bf(acc[i][2]) | ((uint)f2bf(acc[i][3]) << 16);
            pk.z = (uint)f2bf(acc[i][4]) | ((uint)f2bf(acc[i][5]) << 16);
            pk.w = (uint)f2bf(acc[i][6]) | ((uint)f2bf(acc[i][7]) << 16);
            *reinterpret_cast<uint4*>(h + (size_t)n * HID + c0) = pk;
        }
    }

    // ---- epilogue 2: fused attention scores ----
    {
        int head = c0 >> 5;                 // this thread's 8 channels live in one head
        int cc0  = c0 & 31;
        const float* as = att + head * (2 * OUT_CH) + cc0;
        const float* ad = as + OUT_CH;
        float av[8], dv[8];
#pragma unroll
        for (int j = 0; j < 8; j++) { av[j] = as[j]; dv[j] = ad[j]; }
#pragma unroll
        for (int i = 0; i < 4; i++) {
            float pss = 0.f, psd = 0.f;
#pragma unroll
            for (int j = 0; j < 8; j++) {
                pss = fmaf(acc[i][j], av[j], pss);
                psd = fmaf(acc[i][j], dv[j], psd);
            }
            atomicAdd(&sred[n0 + i][head * 2], pss);
            atomicAdd(&sred[n0 + i][head * 2 + 1], psd);
        }
        __syncthreads();
#pragma unroll
        for (int l = 0; l < 2; l++) {
            int idx = tid + l * 256;        // 0..511
            int node = idx >> 3, slot = idx & 7;
            int n = nodeBase + node;
            if (n < N_NODES) {
                float v = sred[node][slot];
                int hd = slot >> 1;
                if (slot & 1) s_dst[n * HEADS + hd] = v;
                else          s_src[n * HEADS + hd] = v;
            }
        }
    }
}

// ---------------- CSR build, level 1a: per-block bucket histogram (transposed store) ----------------
__global__ __launch_bounds__(256) void k_h0(const int* __restrict__ ei,
                                            int* __restrict__ hist_t) {
    __shared__ int cnt[NBUCK];
    int t = threadIdx.x;
    if (t < NBUCK) cnt[t] = 0;
    __syncthreads();
    int base = blockIdx.x * EPB;
    for (int e = base + t; e < base + EPB; e += 256)
        atomicAdd(&cnt[ei[N_EDGES + e] >> 10], 1);
    __syncthreads();
    if (t < NBUCK) hist_t[t * NBLK + blockIdx.x] = cnt[t];
}

// ---------------- level 1b-i: per-bucket scan over 256 blocks (coalesced, parallel) ----------------
__global__ __launch_bounds__(256) void k_sc0a(int* __restrict__ hist_t,
                                              int* __restrict__ bucket_tot) {
    __shared__ int sm[256];
    int b = blockIdx.x, t = threadIdx.x;
    int v = hist_t[b * NBLK + t];
    sm[t] = v;
    __syncthreads();
    for (int off = 1; off < 256; off <<= 1) {
        int u = (t >= off) ? sm[t - off] : 0;
        __syncthreads();
        sm[t] += u;
        __syncthreads();
    }
    hist_t[b * NBLK + t] = sm[t] - v;       // exclusive intra-bucket prefix
    if (t == 255) bucket_tot[b] = sm[255];
}

// ---------------- level 1b-ii: scan 98 bucket totals ----------------
__global__ __launch_bounds__(128) void k_sc0b(const int* __restrict__ bucket_tot,
                                              int* __restrict__ bucket_base) {
    __shared__ int sm[128];
    int t = threadIdx.x;
    int v = (t < NBUCK) ? bucket_tot[t] : 0;
    sm[t] = v;
    __syncthreads();
    for (int off = 1; off < 128; off <<= 1) {
        int u = (t >= off) ? sm[t - off] : 0;
        __syncthreads();
        sm[t] += u;
        __syncthreads();
    }
    if (t < NBUCK) bucket_base[t] = sm[t] - v;
    if (t == 0) bucket_base[NBUCK] = N_EDGES;
}

// ---------------- level 1c: scatter into bucket-sorted packed array ----------------
__global__ __launch_bounds__(256) void k_b1(const int* __restrict__ ei,
                                            const int* __restrict__ hist_t,
                                            const int* __restrict__ bucket_base,
                                            int* __restrict__ packed) {
    __shared__ int cur[NBUCK];
    int t = threadIdx.x;
    if (t < NBUCK) cur[t] = bucket_base[t] + hist_t[t * NBLK + blockIdx.x];
    __syncthreads();
    int base = blockIdx.x * EPB;
    for (int e = base + t; e < base + EPB; e += 256) {
        int src = ei[e], dst = ei[N_EDGES + e];
        int pos = atomicAdd(&cur[dst >> 10], 1);
        packed[pos] = (src << 10) | (dst & (BNODES - 1));   // src < 2^17, fits
    }
}

// ---------------- level 2: per-bucket exact CSR + row_start ----------------
__global__ __launch_bounds__(256) void k_b2(const int* __restrict__ packed,
                                            const int* __restrict__ bucket_base,
                                            int* __restrict__ csr_src,
                                            int* __restrict__ row_start) {
    __shared__ int cnt[BNODES];
    __shared__ int cur[BNODES];
    __shared__ int sm[256];
    int b = blockIdx.x, t = threadIdx.x;
    int beg = bucket_base[b], end = bucket_base[b + 1];
#pragma unroll
    for (int j = 0; j < 4; j++) cnt[t * 4 + j] = 0;
    __syncthreads();
    for (int e = beg + t; e < end; e += 256)
        atomicAdd(&cnt[packed[e] & (BNODES - 1)], 1);
    __syncthreads();
    int c0 = cnt[t * 4], c1 = cnt[t * 4 + 1], c2 = cnt[t * 4 + 2], c3 = cnt[t * 4 + 3];
    int tot = c0 + c1 + c2 + c3;
    sm[t] = tot;
    __syncthreads();
    for (int off = 1; off < 256; off <<= 1) {
        int v = (t >= off) ? sm[t - off] : 0;
        __syncthreads();
        sm[t] += v;
        __syncthreads();
    }
    int p0 = beg + sm[t] - tot;
    int p1 = p0 + c0, p2 = p1 + c1, p3 = p2 + c2;
    cur[t * 4] = p0; cur[t * 4 + 1] = p1; cur[t * 4 + 2] = p2; cur[t * 4 + 3] = p3;
    int nodeb = b * BNODES + t * 4;
    int pv[4] = {p0, p1, p2, p3};
#pragma unroll
    for (int j = 0; j < 4; j++)
        if (nodeb + j <= N_NODES) row_start[nodeb + j] = pv[j];
    __syncthreads();
    for (int e = beg + t; e < end; e += 256) {
        int pk = packed[e];
        int pos = atomicAdd(&cur[pk & (BNODES - 1)], 1);
        csr_src[pos] = pk >> 10;
    }
}

// ---------------- K5: gather aggregation — one wave (64 threads) per node ----------------
__global__ __launch_bounds__(64) void k_agg(const int* __restrict__ row_start,
                                            const int* __restrict__ csr_src,
                                            const float* __restrict__ s_src,
                                            const float* __restrict__ s_dst,
                                            const ushort* __restrict__ h,
                                            const float* __restrict__ bias,
                                            float* __restrict__ out) {
    int n    = blockIdx.x;
    int lane = threadIdx.x;        // 0..63
    int head = lane >> 4;          // 16 lanes per head
    float sdh = s_dst[n * HEADS + head];
    int beg = row_start[n], end = row_start[n + 1];
    const uint* hrow = reinterpret_cast<const uint*>(h);   // bf16x2 per uint

    float acc0 = 0.f, acc1 = 0.f, sum_w = 0.f;
#pragma unroll 4
    for (int j = beg; j < end; j++) {
        int src = csr_src[j];                       // wave-uniform broadcast
        float ss = s_src[src * HEADS + head];       // L2-resident table
        float a  = ss + sdh;
        a = a >= 0.f ? a : NEG_SLOPE * a;
        float wgt = __expf(a);
        sum_w += wgt;
        uint u = hrow[(size_t)src * (HID / 2) + lane];  // 2 bf16 channels
        acc0 = fmaf(wgt, __uint_as_float(u << 16), acc0);
        acc1 = fmaf(wgt, __uint_as_float(u & 0xFFFF0000u), acc1);
    }
    float inv = 1.0f / (sum_w + 1e-16f);
    int ch = lane * 2;
    float2 bv = *reinterpret_cast<const float2*>(bias + ch);
    float2 o;
    o.x = acc0 * inv + bv.x;
    o.y = acc1 * inv + bv.y;
    *reinterpret_cast<float2*>(out + (size_t)n * HID + ch) = o;
}

extern "C" void kernel_launch(void* const* d_in, const int* in_sizes, int n_in,
                              void* d_out, int out_size, void* d_ws, size_t ws_size,
                              hipStream_t stream) {
    const float* x    = (const float*)d_in[0];
    const int*   ei   = (const int*)  d_in[1];
    const float* w    = (const float*)d_in[2];
    const float* att  = (const float*)d_in[3];
    const float* bias = (const float*)d_in[4];
    float* out = (float*)d_out;

    char* p = (char*)d_ws;
    float* s_src    = (float*)p;  p += (size_t)N_NODES * HEADS * 4;   // 1.6 MB
    float* s_dst    = (float*)p;  p += (size_t)N_NODES * HEADS * 4;   // 1.6 MB
    ushort* h       = (ushort*)p; p += (size_t)N_NODES * HID * 2;     // 25.6 MB (16B-aligned)
    int* csr_src    = (int*)p;    p += (size_t)N_EDGES * 4;           // 6.4 MB
    int* packed     = (int*)p;    p += (size_t)N_EDGES * 4;           // 6.4 MB
    int* hist_t     = (int*)p;    p += (size_t)NBUCK * NBLK * 4;      // 100 KB
    int* row_start  = (int*)p;    p += (size_t)(N_NODES + 1) * 4;
    int* bucket_tot = (int*)p;    p += (size_t)NBUCK * 4;
    int* bucket_base= (int*)p;    p += (size_t)(NBUCK + 1) * 4;

    k_gemm<<<(N_NODES + BM - 1) / BM, 256, 0, stream>>>(x, w, att, h, s_src, s_dst);
    k_h0<<<NBLK, 256, 0, stream>>>(ei, hist_t);
    k_sc0a<<<NBUCK, 256, 0, stream>>>(hist_t, bucket_tot);
    k_sc0b<<<1, 128, 0, stream>>>(bucket_tot, bucket_base);
    k_b1<<<NBLK, 256, 0, stream>>>(ei, hist_t, bucket_base, packed);
    k_b2<<<NBUCK, 256, 0, stream>>>(packed, bucket_base, csr_src, row_start);
    k_agg<<<N_NODES, 64, 0, stream>>>(row_start, csr_src, s_src, s_dst, h, bias, out);
}